// Round 8
// baseline (159.292 us; speedup 1.0000x reference)
//
#include <hip/hip_runtime.h>
#include <math.h>

#define N_NODES 20000
#define N_EDGES 640000
#define NMAX 8
#define NUM_BASIS 928
#define CAP 72            // record slots per node; Poisson(32), 7 sigma -> P(drop) ~1e-7
#define TR 72             // f16 LDS row stride (k-dim), 144 B -> bank-spread, 16B-aligned
#define NBLK 256          // binning blocks; CHUNK = N_EDGES/NBLK edges each
#define CHUNK (N_EDGES / NBLK)          // 2500
#define BINT 512          // threads per binning block (8 waves)
#define TPB 256
#define WPB 4             // waves per block in node kernel, one node-pair per wave
#define NPAIRS (N_NODES / 2)
#define SCAN_B 1024
#define SCAN_NB ((N_NODES + SCAN_B - 1) / SCAN_B)   // 20

typedef _Float16 half8 __attribute__((ext_vector_type(8)));
typedef float floatx4 __attribute__((ext_vector_type(4)));

// wave-local LDS sync (independent waves, private LDS regions; guide rule #18)
__device__ __forceinline__ void wsync() {
    asm volatile("s_waitcnt lgkmcnt(0)" ::: "memory");
    __builtin_amdgcn_sched_barrier(0);
}

// ================= primary: atomic-free two-pass stable binning ==============
// Measured invariant (R1/R2/R7): any kernel with 640K device-scope atomicAdds
// costs ~48-51us (13G atomics/s fabric ceiling) regardless of payload/locality.
// Replace with per-block LDS histograms + column prefix + LDS-rank scatter:
// ZERO global atomics anywhere in the primary path.

// pass 1: per-block histogram of receivers -> gcounts[block][node]
__global__ __launch_bounds__(BINT) void hist_kernel(
    const int* __restrict__ receivers,
    int* __restrict__ gcounts)           // [NBLK][N_NODES]
{
    __shared__ int h[N_NODES];           // 80 KB
    int tid = threadIdx.x, b = blockIdx.x;
    for (int i = tid; i < N_NODES; i += BINT) h[i] = 0;
    __syncthreads();
    int e0 = b * CHUNK;
    for (int i = tid; i < CHUNK; i += BINT)
        atomicAdd(&h[receivers[e0 + i]], 1);          // LDS atomic (cheap)
    __syncthreads();
    int* dst = gcounts + (size_t)b * N_NODES;
    for (int i = tid; i < N_NODES; i += BINT) dst[i] = h[i];
}

// pass 2: per-node exclusive prefix across blocks (in-place) + totals
__global__ __launch_bounds__(256) void scan_cols(
    int* __restrict__ gcounts,           // in: counts, out: per-block bases
    int* __restrict__ counts)            // [N_NODES] totals
{
    int n = blockIdx.x * 256 + threadIdx.x;
    if (n >= N_NODES) return;
    int run = 0;
    #pragma unroll 8
    for (int b = 0; b < NBLK; ++b) {
        size_t idx = (size_t)b * N_NODES + n;
        int v = gcounts[idx];
        gcounts[idx] = run;
        run += v;
    }
    counts[n] = run;
}

// pass 3: deterministic scatter; rank = block base (LDS) + LDS-atomic local rank
__global__ __launch_bounds__(BINT) void bin_scatter(
    const float* __restrict__ vectors,
    const int* __restrict__ senders,
    const int* __restrict__ receivers,
    const int* __restrict__ species,
    const int* __restrict__ gbase,       // [NBLK][N_NODES] (scanned gcounts)
    float4* __restrict__ feat)           // [N_NODES][CAP] records {vx,vy,vz,zs}
{
    __shared__ int cur[N_NODES];         // 80 KB running cursors
    int tid = threadIdx.x, b = blockIdx.x;
    const int* src = gbase + (size_t)b * N_NODES;
    for (int i = tid; i < N_NODES; i += BINT) cur[i] = src[i];
    __syncthreads();
    int e0 = b * CHUNK;
    for (int i = tid; i < CHUNK; i += BINT) {
        int e = e0 + i;
        int rcv = receivers[e];
        int pos = atomicAdd(&cur[rcv], 1);            // LDS atomic only
        if (pos < CAP) {
            float4 rec;
            rec.x = vectors[3*e+0];
            rec.y = vectors[3*e+1];
            rec.z = vectors[3*e+2];
            rec.w = __int_as_float(species[senders[e]]);
            feat[(size_t)rcv * CAP + pos] = rec;
        }
    }
}

// ================= fallback path: exact CSR of records =======================
__global__ __launch_bounds__(256) void count_kernel(const int* __restrict__ receivers,
                                                    int* __restrict__ counts) {
    int e = blockIdx.x * blockDim.x + threadIdx.x;
    if (e < N_EDGES) atomicAdd(&counts[receivers[e]], 1);
}

__global__ __launch_bounds__(SCAN_B) void scan_blocks(const int* __restrict__ counts,
                                                      int* __restrict__ prefix,
                                                      int* __restrict__ blockSums) {
    int tid = threadIdx.x;
    int gid = blockIdx.x * SCAN_B + tid;
    int c = (gid < N_NODES) ? counts[gid] : 0;
    int lane = tid & 63, wave = tid >> 6;
    int s = c;
    #pragma unroll
    for (int off = 1; off < 64; off <<= 1) {
        int v = __shfl_up(s, off);
        if (lane >= off) s += v;
    }
    __shared__ int waveTot[16];
    __shared__ int waveExcl[16];
    if (lane == 63) waveTot[wave] = s;
    __syncthreads();
    if (tid == 0) {
        int run = 0;
        #pragma unroll
        for (int ww = 0; ww < 16; ++ww) { waveExcl[ww] = run; run += waveTot[ww]; }
        blockSums[blockIdx.x] = run;
    }
    __syncthreads();
    int excl = (s - c) + waveExcl[wave];
    if (gid < N_NODES) prefix[gid] = excl;
}

__global__ __launch_bounds__(SCAN_B) void scan_finalize(const int* __restrict__ prefix,
                                                        const int* __restrict__ blockSums,
                                                        int* __restrict__ offsets,
                                                        int* __restrict__ cursors) {
    __shared__ int blockOff;
    int tid = threadIdx.x;
    if (tid == 0) {
        int run = 0;
        for (int b = 0; b < blockIdx.x; ++b) run += blockSums[b];
        blockOff = run;
    }
    __syncthreads();
    int gid = blockIdx.x * SCAN_B + tid;
    if (gid < N_NODES) {
        int v = prefix[gid] + blockOff;
        offsets[gid] = v;
        cursors[gid] = v;
    }
}

__global__ __launch_bounds__(256) void scatter_rec_kernel(
    const float* __restrict__ vectors,
    const int* __restrict__ senders,
    const int* __restrict__ receivers,
    const int* __restrict__ species,
    int* __restrict__ cursors,
    float4* __restrict__ feat)
{
    int e = blockIdx.x * 256 + threadIdx.x;
    if (e >= N_EDGES) return;
    int rcv = receivers[e];
    int pos = atomicAdd(&cursors[rcv], 1);
    float4 rec;
    rec.x = vectors[3*e+0];
    rec.y = vectors[3*e+1];
    rec.z = vectors[3*e+2];
    rec.w = __int_as_float(species[senders[e]]);
    feat[pos] = rec;
}

// ================= MFMA node kernel (R7-verified, UNCHANGED) =================
template<bool SLICED>
__global__ __launch_bounds__(TPB, 5) void ace_node_kernel(
    const float4* __restrict__ feat,
    const int* __restrict__ counts,     // [N_NODES]
    const int* __restrict__ offsets,    // CSR only
    const int* __restrict__ species,
    const float* __restrict__ node_mask,
    const float* __restrict__ wA,
    const float* __restrict__ c_pair,
    const float* __restrict__ c_read,
    const float* __restrict__ E0,
    float* __restrict__ outE,
    float* __restrict__ outB)
{
    int tid = threadIdx.x;
    int w = tid >> 6, lane = tid & 63;
    int row = lane & 15, quad = lane >> 4;

    __shared__ __align__(16) _Float16 sOps[WPB][2][16 * TR];  // [w][0]=WRT,[w][1]=YT
    __shared__ float sWA[64];
    __shared__ float sCPall[512];                              // full c_pair [8][8][8]

    if (tid < 64) sWA[tid] = wA[tid];
    sCPall[tid]       = c_pair[tid];
    sCPall[tid + 256] = c_pair[tid + 256];
    __syncthreads();                      // uniform, once, before waves diverge

    _Float16* sWRT = &sOps[w][0][0];
    _Float16* sYT  = &sOps[w][1][0];

    int p = blockIdx.x * WPB + w;
    if (p >= NPAIRS) return;
    int n0 = p * 2, n1 = n0 + 1;
    int z0 = species[n0], z1 = species[n1];

    int c0, c1;
    size_t base0, base1;
    if (SLICED) {
        c0 = min(counts[n0], CAP);
        c1 = min(counts[n1], CAP);
        base0 = (size_t)n0 * CAP;
        base1 = (size_t)n1 * CAP;
    } else {
        c0 = counts[n0]; c1 = counts[n1];
        base0 = (size_t)offsets[n0]; base1 = (size_t)offsets[n1];
    }
    int total = c0 + c1;

    floatx4 acc = {0.0f, 0.0f, 0.0f, 0.0f};
    float ep0 = 0.0f, ep1 = 0.0f;

    for (int base = 0; base < total; base += 64) {
        int j = base + lane;
        bool active = j < total;
        int node = (j >= c0) ? 1 : 0;

        half8 wrh;
        #pragma unroll
        for (int a = 0; a < 8; ++a) wrh[a] = (_Float16)0.0f;
        float Yf[16];
        #pragma unroll
        for (int m = 0; m < 16; ++m) Yf[m] = 0.0f;

        if (active) {
            int jj = node ? (j - c0) : j;
            size_t slot = (node ? base1 : base0) + jj;
            float4 rec = feat[slot];                 // piecewise-contiguous read
            float vx = rec.x, vy = rec.y, vz = rec.z;
            int zs = __float_as_int(rec.w);

            float r2 = vx*vx + vy*vy + vz*vz + 1e-12f;
            float invr = rsqrtf(r2);
            float r  = r2 * invr;
            float dd = r * 0.2f;                   // r / RCUT
            float d2 = dd*dd, d6 = d2*d2*d2;
            float env = 1.0f + d6 * (-28.0f + 48.0f*dd - 21.0f*d2);  // p=6 envelope
            env = (dd < 1.0f) ? env : 0.0f;
            float pref = 0.6324555320336759f * invr * env;  // sqrt(2/RCUT)*env/r

            float x = 3.14159265358979f * dd;      // in [0, pi]
            float sp = __sinf(x), cp = __cosf(x);
            float twoc = 2.0f * cp;
            float Rn[NMAX];
            float s_prev = 0.0f, s_cur = sp;
            Rn[0] = pref * s_cur;
            #pragma unroll
            for (int nq = 1; nq < NMAX; ++nq) {
                float s_next = twoc * s_cur - s_prev;
                s_prev = s_cur; s_cur = s_next;
                Rn[nq] = pref * s_cur;
            }

            int zr = node ? z1 : z0;
            float ep = 0.0f;
            #pragma unroll
            for (int nq = 0; nq < NMAX; ++nq) ep += sCPall[(zr*8 + zs)*8 + nq] * Rn[nq];
            if (node) ep1 += 0.5f * ep; else ep0 += 0.5f * ep;

            #pragma unroll
            for (int a = 0; a < NMAX; ++a) wrh[a] = (_Float16)(sWA[zs*8+a] * Rn[a]);

            float ux = vx*invr, uy = vy*invr, uz = vz*invr;
            float xx = ux*ux, yy = uy*uy, zz = uz*uz;
            Yf[0]  = 0.28209479177387814f;
            Yf[1]  = 0.4886025119029199f  * uy;
            Yf[2]  = 0.4886025119029199f  * uz;
            Yf[3]  = 0.4886025119029199f  * ux;
            Yf[4]  = 1.0925484305920792f  * ux * uy;
            Yf[5]  = 1.0925484305920792f  * uy * uz;
            Yf[6]  = 0.31539156525252005f * (3.0f*zz - 1.0f);
            Yf[7]  = 1.0925484305920792f  * ux * uz;
            Yf[8]  = 0.5462742152960396f  * (xx - yy);
            Yf[9]  = 0.5900435899266435f  * uy * (3.0f*xx - yy);
            Yf[10] = 2.890611442640554f   * ux * uy * uz;
            Yf[11] = 0.4570457994644658f  * uy * (5.0f*zz - 1.0f);
            Yf[12] = 0.3731763325901154f  * uz * (5.0f*zz - 3.0f);
            Yf[13] = 0.4570457994644658f  * ux * (5.0f*zz - 1.0f);
            Yf[14] = 1.445305721320277f   * uz * (xx - yy);
            Yf[15] = 0.5900435899266435f  * ux * (xx - 3.0f*yy);
        }

        // transpose into MFMA operand layout; zero the other node's a-rows
        int rb = node * 8;
        #pragma unroll
        for (int a = 0; a < 8; ++a) {
            sWRT[(rb + a) * TR + lane]       = wrh[a];
            sWRT[((rb ^ 8) + a) * TR + lane] = (_Float16)0.0f;
        }
        #pragma unroll
        for (int m = 0; m < 16; ++m) sYT[m * TR + lane] = (_Float16)Yf[m];
        wsync();

        acc = __builtin_amdgcn_mfma_f32_16x16x32_f16(
            *(const half8*)&sWRT[row * TR + quad * 8],
            *(const half8*)&sYT [row * TR + quad * 8], acc, 0, 0, 0);
        if (total - base > 32)
            acc = __builtin_amdgcn_mfma_f32_16x16x32_f16(
                *(const half8*)&sWRT[row * TR + 32 + quad * 8],
                *(const half8*)&sYT [row * TR + 32 + quad * 8], acc, 0, 0, 0);
        wsync();
    }

    // epilogue scratch aliases the dead MFMA operand region (per-wave)
    float* sA = (float*)sWRT;            // 256 floats
    float* sP = sA + 256;                // 64 floats

    // D[i=quad*4+rg][j=row]; rows 0..7 node0's A, rows 8..15 node1's A
    #pragma unroll
    for (int rg = 0; rg < 4; ++rg)
        sA[(quad * 4 + rg) * 16 + row] = acc[rg];
    wsync();

    {   // P: all 64 lanes, one (node,a,l) each
        int nd = lane >> 5, a = (lane >> 2) & 7, l = lane & 3;
        int arow = nd * 8 + a;
        int m0 = l * l, m1 = (l + 1) * (l + 1);
        float s = 0.0f;
        for (int m = m0; m < m1; ++m) { float vv = sA[arow * 16 + m]; s += vv * vv; }
        sP[nd * 32 + a * 4 + l] = s;
    }
    wsync();

    // B + E: half-wave per node, float4-vectorized
    int nd = lane >> 5, l32 = lane & 31;
    int n = nd ? n1 : n0;
    int z = nd ? z1 : z0;
    const float* sPn = sP + nd * 32;
    const floatx4* cr4 = (const floatx4*)(c_read + (size_t)z * NUM_BASIS);
    floatx4* Brow4 = (floatx4*)(outB + (size_t)n * NUM_BASIS);
    float Ep = 0.0f;
    #pragma unroll
    for (int it = 0; it < 8; ++it) {
        int fi = l32 + it * 32;            // float4 index, NUM_BASIS/4 = 232
        if (fi < 232) {
            floatx4 B;
            if (fi < 8) {                  // B1 part: P flat
                B = *(const floatx4*)&sPn[fi * 4];
            } else {                       // Q part: P[a,l] * P[o, 0..3]
                int t = fi - 8;            // = a*28 + l*7 + k
                int k = t % 7;
                int t2 = t / 7;            // = a*4 + l
                int l = t2 & 3, a = t2 >> 2;
                int o = k + (k >= a ? 1 : 0);
                float pp = sPn[a * 4 + l];
                floatx4 po = *(const floatx4*)&sPn[o * 4];
                B = pp * po;
            }
            __builtin_nontemporal_store(B, &Brow4[fi]);   // write-once output
            floatx4 c = cr4[fi];
            Ep += B[0]*c[0] + B[1]*c[1] + B[2]*c[2] + B[3]*c[3];
        }
    }
    #pragma unroll
    for (int off = 16; off > 0; off >>= 1) Ep += __shfl_down(Ep, off);
    #pragma unroll
    for (int off = 1; off < 64; off <<= 1) {
        ep0 += __shfl_xor(ep0, off);
        ep1 += __shfl_xor(ep1, off);
    }
    if (l32 == 0) {
        float epv = nd ? ep1 : ep0;
        outE[n] = (Ep + epv + E0[z]) * node_mask[n];
    }
}

extern "C" void kernel_launch(void* const* d_in, const int* in_sizes, int n_in,
                              void* d_out, int out_size, void* d_ws, size_t ws_size,
                              hipStream_t stream) {
    const float* vectors   = (const float*)d_in[0];
    const int*   senders   = (const int*)d_in[1];
    const int*   receivers = (const int*)d_in[2];
    const int*   species   = (const int*)d_in[3];
    const float* node_mask = (const float*)d_in[4];
    const float* wA        = (const float*)d_in[5];
    const float* c_read    = (const float*)d_in[6];
    const float* E0        = (const float*)d_in[7];
    const float* c_pair    = (const float*)d_in[8];

    float* outE = (float*)d_out;        // [20000]
    float* outB = outE + N_NODES;       // [20000][928]

    size_t featBytes   = (size_t)N_NODES * CAP * sizeof(float4);             // 23.04 MB
    size_t gcountBytes = (size_t)NBLK * N_NODES * sizeof(int);               // 20.48 MB
    size_t countBytes  = (size_t)N_NODES * sizeof(int);                      // 80 KB
    size_t primaryNeed = featBytes + gcountBytes + countBytes;               // ~43.6 MB
    int nodeGrid = (NPAIRS + WPB - 1) / WPB;                                 // 2500

    if (ws_size >= primaryNeed) {
        // ---- primary: 4 dispatches, zero global atomics, no memset ----
        float4* feat  = (float4*)d_ws;
        int* gcounts  = (int*)((char*)d_ws + featBytes);
        int* counts   = (int*)((char*)d_ws + featBytes + gcountBytes);
        hist_kernel<<<NBLK, BINT, 0, stream>>>(receivers, gcounts);
        scan_cols<<<(N_NODES + 255)/256, 256, 0, stream>>>(gcounts, counts);
        bin_scatter<<<NBLK, BINT, 0, stream>>>(
            vectors, senders, receivers, species, gcounts, feat);
        ace_node_kernel<true><<<nodeGrid, TPB, 0, stream>>>(
            feat, counts, (const int*)nullptr, species, node_mask,
            wA, c_pair, c_read, E0, outE, outB);
    } else {
        // ---- fallback: exact CSR of records (10.24 MB + scan arrays) ----
        float4* feat   = (float4*)d_ws;                    // 640000 recs
        int* counts    = (int*)((char*)d_ws + (size_t)N_EDGES * sizeof(float4));
        int* offsets   = counts + N_NODES;
        int* cursors   = offsets + N_NODES;
        int* prefix    = cursors + N_NODES;
        int* blockSums = prefix + N_NODES;
        hipMemsetAsync(counts, 0, N_NODES * sizeof(int), stream);
        count_kernel<<<(N_EDGES + 255)/256, 256, 0, stream>>>(receivers, counts);
        scan_blocks<<<SCAN_NB, SCAN_B, 0, stream>>>(counts, prefix, blockSums);
        scan_finalize<<<SCAN_NB, SCAN_B, 0, stream>>>(prefix, blockSums, offsets, cursors);
        scatter_rec_kernel<<<(N_EDGES + 255)/256, 256, 0, stream>>>(
            vectors, senders, receivers, species, cursors, feat);
        ace_node_kernel<false><<<nodeGrid, TPB, 0, stream>>>(
            feat, counts, offsets, species, node_mask,
            wA, c_pair, c_read, E0, outE, outB);
    }
}

// Round 9
// 148.155 us; speedup vs baseline: 1.0752x; 1.0752x over previous
//
#include <hip/hip_runtime.h>
#include <math.h>

#define N_NODES 20000
#define N_EDGES 640000
#define NMAX 8
#define NUM_BASIS 928
#define NRANGE 250        // coarse ranges (bins)
#define RNODES 80         // nodes per range; 250*80 = 20000
#define BINCAP 3072       // records per range bin; mean 2560, +10 sigma
#define TR 72             // f16 LDS row stride (k-dim), 144 B -> bank-spread
#define NBLK 256          // binning blocks
#define CHUNK (N_EDGES / NBLK)          // 2500
#define BINT 512          // threads per binning/compute block (8 waves)
#define TPB 256
#define WPB 4
#define NPAIRS (N_NODES / 2)
#define SCAN_B 1024
#define SCAN_NB ((N_NODES + SCAN_B - 1) / SCAN_B)   // 20

typedef _Float16 half8 __attribute__((ext_vector_type(8)));
typedef float floatx4 __attribute__((ext_vector_type(4)));

// wave-local LDS sync (guide rule #18)
__device__ __forceinline__ void wsync() {
    asm volatile("s_waitcnt lgkmcnt(0)" ::: "memory");
    __builtin_amdgcn_sched_barrier(0);
}

// ======================= primary: coalesced range-binning =====================
// Invariant found R0-R8: ~640K random 64B line-touches cost ~45-50us wherever
// they live (scattered stores, gathers, or atomics). This pipeline has NONE:
// all global accesses are coalesced runs or L2-resident tables.

// pass 1: per-block histogram over 250 ranges
__global__ __launch_bounds__(BINT) void hist_kernel(
    const int* __restrict__ receivers,
    int* __restrict__ gcounts)           // [NBLK][NRANGE]
{
    __shared__ int h[NRANGE];
    int tid = threadIdx.x, b = blockIdx.x;
    for (int i = tid; i < NRANGE; i += BINT) h[i] = 0;
    __syncthreads();
    int e0 = b * CHUNK;
    for (int i = tid; i < CHUNK; i += BINT)
        atomicAdd(&h[receivers[e0 + i] / RNODES], 1);   // LDS atomic only
    __syncthreads();
    for (int i = tid; i < NRANGE; i += BINT) gcounts[b * NRANGE + i] = h[i];
}

// pass 2: per-range exclusive prefix across blocks (in-place) + totals
__global__ __launch_bounds__(256) void scan_bins(
    int* __restrict__ gcounts,           // in: counts, out: per-block bases
    int* __restrict__ counts)            // [NRANGE] totals
{
    int bin = blockIdx.x * 256 + threadIdx.x;
    if (bin >= NRANGE) return;
    int run = 0;
    for (int b = 0; b < NBLK; ++b) {
        int idx = b * NRANGE + bin;
        int v = gcounts[idx];
        gcounts[idx] = run;
        run += v;
    }
    counts[bin] = run;
}

// pass 3: scatter records into range bins; per (block,bin) writes are
// CONSECUTIVE slots (~10 per bin per block) -> ~4x fewer line touches,
// zero global atomics (LDS cursors preloaded with scanned bases).
__global__ __launch_bounds__(BINT) void bin_scatter(
    const float* __restrict__ vectors,
    const int* __restrict__ senders,
    const int* __restrict__ receivers,
    const int* __restrict__ species,
    const int* __restrict__ gbase,       // [NBLK][NRANGE]
    float4* __restrict__ binned)         // [NRANGE][BINCAP]
{
    __shared__ int cur[NRANGE];
    int tid = threadIdx.x, b = blockIdx.x;
    for (int i = tid; i < NRANGE; i += BINT) cur[i] = gbase[b * NRANGE + i];
    __syncthreads();
    int e0 = b * CHUNK;
    for (int i = tid; i < CHUNK; i += BINT) {
        int e = e0 + i;
        int rcv = receivers[e];
        int bin = rcv / RNODES;
        int nl  = rcv - bin * RNODES;                  // 0..79
        int pos = atomicAdd(&cur[bin], 1);             // LDS atomic only
        if (pos < BINCAP) {
            int zs = species[senders[e]];              // 80KB table, L2-hot
            float4 rec;
            rec.x = vectors[3*e+0];
            rec.y = vectors[3*e+1];
            rec.z = vectors[3*e+2];
            rec.w = __int_as_float((zs << 7) | nl);
            binned[(size_t)bin * BINCAP + pos] = rec;
        }
    }
}

// pass 4: one block per range. Contiguous bin read -> LDS counting-sort by
// node (exact, no drops) -> R7-verified per-wave pair compute from LDS.
__global__ __launch_bounds__(BINT, 1) void range_compute(
    const float4* __restrict__ binned,
    const int* __restrict__ counts,      // [NRANGE]
    const int* __restrict__ species,
    const float* __restrict__ node_mask,
    const float* __restrict__ wA,
    const float* __restrict__ c_pair,
    const float* __restrict__ c_read,
    const float* __restrict__ E0,
    float* __restrict__ outE,
    float* __restrict__ outB)
{
    __shared__ __align__(16) float4 sRec[BINCAP];               // 48 KB
    __shared__ __align__(16) _Float16 sOps[8][2][16 * TR];      // 36.9 KB
    __shared__ int sHist[RNODES];
    __shared__ int sOff[RNODES + 1];
    __shared__ int sCur[RNODES];
    __shared__ float sWA[64];
    __shared__ float sCPall[512];

    int tid = threadIdx.x;
    int w = tid >> 6, lane = tid & 63;
    int row = lane & 15, quad = lane >> 4;
    int r = blockIdx.x;

    if (tid < 64) sWA[tid] = wA[tid];
    if (tid < 256) { sCPall[tid] = c_pair[tid]; sCPall[tid + 256] = c_pair[tid + 256]; }
    for (int i = tid; i < RNODES; i += BINT) sHist[i] = 0;
    __syncthreads();

    int cnt = min(counts[r], BINCAP);
    const float4* src = binned + (size_t)r * BINCAP;

    // histogram of node-local ids
    for (int i = tid; i < cnt; i += BINT) {
        int wv = __float_as_int(src[i].w);
        atomicAdd(&sHist[wv & 127], 1);
    }
    __syncthreads();
    if (tid == 0) {                       // 80-entry serial prefix
        int run = 0;
        for (int i = 0; i < RNODES; ++i) { sOff[i] = run; run += sHist[i]; }
        sOff[RNODES] = run;
    }
    __syncthreads();
    for (int i = tid; i < RNODES; i += BINT) sCur[i] = sOff[i];
    __syncthreads();
    // stable-ish scatter into sorted LDS layout (order within node irrelevant:
    // segment_sum is order-insensitive up to FP rounding, same as atomics were)
    for (int i = tid; i < cnt; i += BINT) {
        float4 rec = src[i];              // second read: L2-hot
        int nl = __float_as_int(rec.w) & 127;
        int pos = atomicAdd(&sCur[nl], 1);
        sRec[pos] = rec;
    }
    __syncthreads();

    _Float16* sWRT = &sOps[w][0][0];
    _Float16* sYT  = &sOps[w][1][0];

    // 40 pairs / 8 waves = 5 sequential pairs per wave (uniform trip count)
    for (int pi = w; pi < RNODES / 2; pi += 8) {
        wsync();                          // sWRT alias reuse across pairs
        int nl0 = pi * 2, nl1 = nl0 + 1;
        int n0 = r * RNODES + nl0, n1 = n0 + 1;
        int z0 = species[n0], z1 = species[n1];
        int b0 = sOff[nl0], b1 = sOff[nl1];
        int c0 = b1 - b0, c1 = sOff[nl1 + 1] - b1;
        int total = c0 + c1;

        floatx4 acc = {0.0f, 0.0f, 0.0f, 0.0f};
        float ep0 = 0.0f, ep1 = 0.0f;

        for (int base = 0; base < total; base += 64) {
            int j = base + lane;
            bool active = j < total;
            int node = (j >= c0) ? 1 : 0;

            half8 wrh;
            #pragma unroll
            for (int a = 0; a < 8; ++a) wrh[a] = (_Float16)0.0f;
            float Yf[16];
            #pragma unroll
            for (int m = 0; m < 16; ++m) Yf[m] = 0.0f;

            if (active) {
                int jj = node ? (j - c0) : j;
                float4 rec = sRec[(node ? b1 : b0) + jj];   // LDS, grouped
                float vx = rec.x, vy = rec.y, vz = rec.z;
                int zs = __float_as_int(rec.w) >> 7;

                float r2 = vx*vx + vy*vy + vz*vz + 1e-12f;
                float invr = rsqrtf(r2);
                float rr = r2 * invr;
                float dd = rr * 0.2f;                  // r / RCUT
                float d2 = dd*dd, d6 = d2*d2*d2;
                float env = 1.0f + d6 * (-28.0f + 48.0f*dd - 21.0f*d2);
                env = (dd < 1.0f) ? env : 0.0f;
                float pref = 0.6324555320336759f * invr * env;

                float x = 3.14159265358979f * dd;
                float sp = __sinf(x), cp = __cosf(x);
                float twoc = 2.0f * cp;
                float Rn[NMAX];
                float s_prev = 0.0f, s_cur = sp;
                Rn[0] = pref * s_cur;
                #pragma unroll
                for (int nq = 1; nq < NMAX; ++nq) {
                    float s_next = twoc * s_cur - s_prev;
                    s_prev = s_cur; s_cur = s_next;
                    Rn[nq] = pref * s_cur;
                }

                int zr = node ? z1 : z0;
                float ep = 0.0f;
                #pragma unroll
                for (int nq = 0; nq < NMAX; ++nq) ep += sCPall[(zr*8 + zs)*8 + nq] * Rn[nq];
                if (node) ep1 += 0.5f * ep; else ep0 += 0.5f * ep;

                #pragma unroll
                for (int a = 0; a < NMAX; ++a) wrh[a] = (_Float16)(sWA[zs*8+a] * Rn[a]);

                float ux = vx*invr, uy = vy*invr, uz = vz*invr;
                float xx = ux*ux, yy = uy*uy, zz = uz*uz;
                Yf[0]  = 0.28209479177387814f;
                Yf[1]  = 0.4886025119029199f  * uy;
                Yf[2]  = 0.4886025119029199f  * uz;
                Yf[3]  = 0.4886025119029199f  * ux;
                Yf[4]  = 1.0925484305920792f  * ux * uy;
                Yf[5]  = 1.0925484305920792f  * uy * uz;
                Yf[6]  = 0.31539156525252005f * (3.0f*zz - 1.0f);
                Yf[7]  = 1.0925484305920792f  * ux * uz;
                Yf[8]  = 0.5462742152960396f  * (xx - yy);
                Yf[9]  = 0.5900435899266435f  * uy * (3.0f*xx - yy);
                Yf[10] = 2.890611442640554f   * ux * uy * uz;
                Yf[11] = 0.4570457994644658f  * uy * (5.0f*zz - 1.0f);
                Yf[12] = 0.3731763325901154f  * uz * (5.0f*zz - 3.0f);
                Yf[13] = 0.4570457994644658f  * ux * (5.0f*zz - 1.0f);
                Yf[14] = 1.445305721320277f   * uz * (xx - yy);
                Yf[15] = 0.5900435899266435f  * ux * (xx - 3.0f*yy);
            }

            int rb = node * 8;
            #pragma unroll
            for (int a = 0; a < 8; ++a) {
                sWRT[(rb + a) * TR + lane]       = wrh[a];
                sWRT[((rb ^ 8) + a) * TR + lane] = (_Float16)0.0f;
            }
            #pragma unroll
            for (int m = 0; m < 16; ++m) sYT[m * TR + lane] = (_Float16)Yf[m];
            wsync();

            acc = __builtin_amdgcn_mfma_f32_16x16x32_f16(
                *(const half8*)&sWRT[row * TR + quad * 8],
                *(const half8*)&sYT [row * TR + quad * 8], acc, 0, 0, 0);
            if (total - base > 32)
                acc = __builtin_amdgcn_mfma_f32_16x16x32_f16(
                    *(const half8*)&sWRT[row * TR + 32 + quad * 8],
                    *(const half8*)&sYT [row * TR + 32 + quad * 8], acc, 0, 0, 0);
            wsync();
        }

        // epilogue scratch aliases the dead MFMA operand region (per-wave)
        float* sA = (float*)sWRT;
        float* sP = sA + 256;

        #pragma unroll
        for (int rg = 0; rg < 4; ++rg)
            sA[(quad * 4 + rg) * 16 + row] = acc[rg];
        wsync();

        {   // P: all 64 lanes, one (node,a,l) each
            int nd = lane >> 5, a = (lane >> 2) & 7, l = lane & 3;
            int arow = nd * 8 + a;
            int m0 = l * l, m1 = (l + 1) * (l + 1);
            float s = 0.0f;
            for (int m = m0; m < m1; ++m) { float vv = sA[arow * 16 + m]; s += vv * vv; }
            sP[nd * 32 + a * 4 + l] = s;
        }
        wsync();

        int nd = lane >> 5, l32 = lane & 31;
        int n = nd ? n1 : n0;
        int z = nd ? z1 : z0;
        const float* sPn = sP + nd * 32;
        const floatx4* cr4 = (const floatx4*)(c_read + (size_t)z * NUM_BASIS);
        floatx4* Brow4 = (floatx4*)(outB + (size_t)n * NUM_BASIS);
        float Ep = 0.0f;
        #pragma unroll
        for (int it = 0; it < 8; ++it) {
            int fi = l32 + it * 32;
            if (fi < 232) {
                floatx4 B;
                if (fi < 8) {
                    B = *(const floatx4*)&sPn[fi * 4];
                } else {
                    int t = fi - 8;
                    int k = t % 7;
                    int t2 = t / 7;
                    int l = t2 & 3, a = t2 >> 2;
                    int o = k + (k >= a ? 1 : 0);
                    float pp = sPn[a * 4 + l];
                    floatx4 po = *(const floatx4*)&sPn[o * 4];
                    B = pp * po;
                }
                __builtin_nontemporal_store(B, &Brow4[fi]);
                floatx4 c = cr4[fi];
                Ep += B[0]*c[0] + B[1]*c[1] + B[2]*c[2] + B[3]*c[3];
            }
        }
        #pragma unroll
        for (int off = 16; off > 0; off >>= 1) Ep += __shfl_down(Ep, off);
        #pragma unroll
        for (int off = 1; off < 64; off <<= 1) {
            ep0 += __shfl_xor(ep0, off);
            ep1 += __shfl_xor(ep1, off);
        }
        if (l32 == 0) {
            float epv = nd ? ep1 : ep0;
            outE[n] = (Ep + epv + E0[z]) * node_mask[n];
        }
    }
}

// ===================== fallback path: exact CSR (unchanged) ==================
__global__ __launch_bounds__(256) void count_kernel(const int* __restrict__ receivers,
                                                    int* __restrict__ counts) {
    int e = blockIdx.x * blockDim.x + threadIdx.x;
    if (e < N_EDGES) atomicAdd(&counts[receivers[e]], 1);
}

__global__ __launch_bounds__(SCAN_B) void scan_blocks(const int* __restrict__ counts,
                                                      int* __restrict__ prefix,
                                                      int* __restrict__ blockSums) {
    int tid = threadIdx.x;
    int gid = blockIdx.x * SCAN_B + tid;
    int c = (gid < N_NODES) ? counts[gid] : 0;
    int lane = tid & 63, wave = tid >> 6;
    int s = c;
    #pragma unroll
    for (int off = 1; off < 64; off <<= 1) {
        int v = __shfl_up(s, off);
        if (lane >= off) s += v;
    }
    __shared__ int waveTot[16];
    __shared__ int waveExcl[16];
    if (lane == 63) waveTot[wave] = s;
    __syncthreads();
    if (tid == 0) {
        int run = 0;
        #pragma unroll
        for (int ww = 0; ww < 16; ++ww) { waveExcl[ww] = run; run += waveTot[ww]; }
        blockSums[blockIdx.x] = run;
    }
    __syncthreads();
    int excl = (s - c) + waveExcl[wave];
    if (gid < N_NODES) prefix[gid] = excl;
}

__global__ __launch_bounds__(SCAN_B) void scan_finalize(const int* __restrict__ prefix,
                                                        const int* __restrict__ blockSums,
                                                        int* __restrict__ offsets,
                                                        int* __restrict__ cursors) {
    __shared__ int blockOff;
    int tid = threadIdx.x;
    if (tid == 0) {
        int run = 0;
        for (int b = 0; b < blockIdx.x; ++b) run += blockSums[b];
        blockOff = run;
    }
    __syncthreads();
    int gid = blockIdx.x * SCAN_B + tid;
    if (gid < N_NODES) {
        int v = prefix[gid] + blockOff;
        offsets[gid] = v;
        cursors[gid] = v;
    }
}

__global__ __launch_bounds__(256) void scatter_rec_kernel(
    const float* __restrict__ vectors,
    const int* __restrict__ senders,
    const int* __restrict__ receivers,
    const int* __restrict__ species,
    int* __restrict__ cursors,
    float4* __restrict__ feat)
{
    int e = blockIdx.x * 256 + threadIdx.x;
    if (e >= N_EDGES) return;
    int rcv = receivers[e];
    int pos = atomicAdd(&cursors[rcv], 1);
    float4 rec;
    rec.x = vectors[3*e+0];
    rec.y = vectors[3*e+1];
    rec.z = vectors[3*e+2];
    rec.w = __int_as_float(species[senders[e]]);
    feat[pos] = rec;
}

// CSR-consuming node kernel (R7-verified), fallback only
__global__ __launch_bounds__(TPB, 5) void ace_node_csr(
    const float4* __restrict__ feat,
    const int* __restrict__ counts,
    const int* __restrict__ offsets,
    const int* __restrict__ species,
    const float* __restrict__ node_mask,
    const float* __restrict__ wA,
    const float* __restrict__ c_pair,
    const float* __restrict__ c_read,
    const float* __restrict__ E0,
    float* __restrict__ outE,
    float* __restrict__ outB)
{
    int tid = threadIdx.x;
    int w = tid >> 6, lane = tid & 63;
    int row = lane & 15, quad = lane >> 4;

    __shared__ __align__(16) _Float16 sOps[WPB][2][16 * TR];
    __shared__ float sWA[64];
    __shared__ float sCPall[512];

    if (tid < 64) sWA[tid] = wA[tid];
    sCPall[tid]       = c_pair[tid];
    sCPall[tid + 256] = c_pair[tid + 256];
    __syncthreads();

    _Float16* sWRT = &sOps[w][0][0];
    _Float16* sYT  = &sOps[w][1][0];

    int p = blockIdx.x * WPB + w;
    if (p >= NPAIRS) return;
    int n0 = p * 2, n1 = n0 + 1;
    int z0 = species[n0], z1 = species[n1];

    int c0 = counts[n0], c1 = counts[n1];
    size_t base0 = (size_t)offsets[n0], base1 = (size_t)offsets[n1];
    int total = c0 + c1;

    floatx4 acc = {0.0f, 0.0f, 0.0f, 0.0f};
    float ep0 = 0.0f, ep1 = 0.0f;

    for (int base = 0; base < total; base += 64) {
        int j = base + lane;
        bool active = j < total;
        int node = (j >= c0) ? 1 : 0;

        half8 wrh;
        #pragma unroll
        for (int a = 0; a < 8; ++a) wrh[a] = (_Float16)0.0f;
        float Yf[16];
        #pragma unroll
        for (int m = 0; m < 16; ++m) Yf[m] = 0.0f;

        if (active) {
            int jj = node ? (j - c0) : j;
            float4 rec = feat[(node ? base1 : base0) + jj];
            float vx = rec.x, vy = rec.y, vz = rec.z;
            int zs = __float_as_int(rec.w);

            float r2 = vx*vx + vy*vy + vz*vz + 1e-12f;
            float invr = rsqrtf(r2);
            float rr = r2 * invr;
            float dd = rr * 0.2f;
            float d2 = dd*dd, d6 = d2*d2*d2;
            float env = 1.0f + d6 * (-28.0f + 48.0f*dd - 21.0f*d2);
            env = (dd < 1.0f) ? env : 0.0f;
            float pref = 0.6324555320336759f * invr * env;

            float x = 3.14159265358979f * dd;
            float sp = __sinf(x), cp = __cosf(x);
            float twoc = 2.0f * cp;
            float Rn[NMAX];
            float s_prev = 0.0f, s_cur = sp;
            Rn[0] = pref * s_cur;
            #pragma unroll
            for (int nq = 1; nq < NMAX; ++nq) {
                float s_next = twoc * s_cur - s_prev;
                s_prev = s_cur; s_cur = s_next;
                Rn[nq] = pref * s_cur;
            }

            int zr = node ? z1 : z0;
            float ep = 0.0f;
            #pragma unroll
            for (int nq = 0; nq < NMAX; ++nq) ep += sCPall[(zr*8 + zs)*8 + nq] * Rn[nq];
            if (node) ep1 += 0.5f * ep; else ep0 += 0.5f * ep;

            #pragma unroll
            for (int a = 0; a < NMAX; ++a) wrh[a] = (_Float16)(sWA[zs*8+a] * Rn[a]);

            float ux = vx*invr, uy = vy*invr, uz = vz*invr;
            float xx = ux*ux, yy = uy*uy, zz = uz*uz;
            Yf[0]  = 0.28209479177387814f;
            Yf[1]  = 0.4886025119029199f  * uy;
            Yf[2]  = 0.4886025119029199f  * uz;
            Yf[3]  = 0.4886025119029199f  * ux;
            Yf[4]  = 1.0925484305920792f  * ux * uy;
            Yf[5]  = 1.0925484305920792f  * uy * uz;
            Yf[6]  = 0.31539156525252005f * (3.0f*zz - 1.0f);
            Yf[7]  = 1.0925484305920792f  * ux * uz;
            Yf[8]  = 0.5462742152960396f  * (xx - yy);
            Yf[9]  = 0.5900435899266435f  * uy * (3.0f*xx - yy);
            Yf[10] = 2.890611442640554f   * ux * uy * uz;
            Yf[11] = 0.4570457994644658f  * uy * (5.0f*zz - 1.0f);
            Yf[12] = 0.3731763325901154f  * uz * (5.0f*zz - 3.0f);
            Yf[13] = 0.4570457994644658f  * ux * (5.0f*zz - 1.0f);
            Yf[14] = 1.445305721320277f   * uz * (xx - yy);
            Yf[15] = 0.5900435899266435f  * ux * (xx - 3.0f*yy);
        }

        int rb = node * 8;
        #pragma unroll
        for (int a = 0; a < 8; ++a) {
            sWRT[(rb + a) * TR + lane]       = wrh[a];
            sWRT[((rb ^ 8) + a) * TR + lane] = (_Float16)0.0f;
        }
        #pragma unroll
        for (int m = 0; m < 16; ++m) sYT[m * TR + lane] = (_Float16)Yf[m];
        wsync();

        acc = __builtin_amdgcn_mfma_f32_16x16x32_f16(
            *(const half8*)&sWRT[row * TR + quad * 8],
            *(const half8*)&sYT [row * TR + quad * 8], acc, 0, 0, 0);
        if (total - base > 32)
            acc = __builtin_amdgcn_mfma_f32_16x16x32_f16(
                *(const half8*)&sWRT[row * TR + 32 + quad * 8],
                *(const half8*)&sYT [row * TR + 32 + quad * 8], acc, 0, 0, 0);
        wsync();
    }

    float* sA = (float*)sWRT;
    float* sP = sA + 256;

    #pragma unroll
    for (int rg = 0; rg < 4; ++rg)
        sA[(quad * 4 + rg) * 16 + row] = acc[rg];
    wsync();

    {
        int nd = lane >> 5, a = (lane >> 2) & 7, l = lane & 3;
        int arow = nd * 8 + a;
        int m0 = l * l, m1 = (l + 1) * (l + 1);
        float s = 0.0f;
        for (int m = m0; m < m1; ++m) { float vv = sA[arow * 16 + m]; s += vv * vv; }
        sP[nd * 32 + a * 4 + l] = s;
    }
    wsync();

    int nd = lane >> 5, l32 = lane & 31;
    int n = nd ? n1 : n0;
    int z = nd ? z1 : z0;
    const float* sPn = sP + nd * 32;
    const floatx4* cr4 = (const floatx4*)(c_read + (size_t)z * NUM_BASIS);
    floatx4* Brow4 = (floatx4*)(outB + (size_t)n * NUM_BASIS);
    float Ep = 0.0f;
    #pragma unroll
    for (int it = 0; it < 8; ++it) {
        int fi = l32 + it * 32;
        if (fi < 232) {
            floatx4 B;
            if (fi < 8) {
                B = *(const floatx4*)&sPn[fi * 4];
            } else {
                int t = fi - 8;
                int k = t % 7;
                int t2 = t / 7;
                int l = t2 & 3, a = t2 >> 2;
                int o = k + (k >= a ? 1 : 0);
                float pp = sPn[a * 4 + l];
                floatx4 po = *(const floatx4*)&sPn[o * 4];
                B = pp * po;
            }
            __builtin_nontemporal_store(B, &Brow4[fi]);
            floatx4 c = cr4[fi];
            Ep += B[0]*c[0] + B[1]*c[1] + B[2]*c[2] + B[3]*c[3];
        }
    }
    #pragma unroll
    for (int off = 16; off > 0; off >>= 1) Ep += __shfl_down(Ep, off);
    #pragma unroll
    for (int off = 1; off < 64; off <<= 1) {
        ep0 += __shfl_xor(ep0, off);
        ep1 += __shfl_xor(ep1, off);
    }
    if (l32 == 0) {
        float epv = nd ? ep1 : ep0;
        outE[n] = (Ep + epv + E0[z]) * node_mask[n];
    }
}

extern "C" void kernel_launch(void* const* d_in, const int* in_sizes, int n_in,
                              void* d_out, int out_size, void* d_ws, size_t ws_size,
                              hipStream_t stream) {
    const float* vectors   = (const float*)d_in[0];
    const int*   senders   = (const int*)d_in[1];
    const int*   receivers = (const int*)d_in[2];
    const int*   species   = (const int*)d_in[3];
    const float* node_mask = (const float*)d_in[4];
    const float* wA        = (const float*)d_in[5];
    const float* c_read    = (const float*)d_in[6];
    const float* E0        = (const float*)d_in[7];
    const float* c_pair    = (const float*)d_in[8];

    float* outE = (float*)d_out;        // [20000]
    float* outB = outE + N_NODES;       // [20000][928]

    size_t binnedBytes = (size_t)NRANGE * BINCAP * sizeof(float4);           // 12.29 MB
    size_t gcountBytes = (size_t)NBLK * NRANGE * sizeof(int);                // 256 KB
    size_t countBytes  = (size_t)NRANGE * sizeof(int);                       // 1 KB
    size_t primaryNeed = binnedBytes + gcountBytes + countBytes;             // ~12.6 MB

    if (ws_size >= primaryNeed) {
        // ---- primary: 4 dispatches, no memset, no global atomics,
        //      no random 64B line-touches ----
        float4* binned = (float4*)d_ws;
        int* gcounts   = (int*)((char*)d_ws + binnedBytes);
        int* counts    = (int*)((char*)d_ws + binnedBytes + gcountBytes);
        hist_kernel<<<NBLK, BINT, 0, stream>>>(receivers, gcounts);
        scan_bins<<<(NRANGE + 255)/256, 256, 0, stream>>>(gcounts, counts);
        bin_scatter<<<NBLK, BINT, 0, stream>>>(
            vectors, senders, receivers, species, gcounts, binned);
        range_compute<<<NRANGE, BINT, 0, stream>>>(
            binned, counts, species, node_mask, wA, c_pair, c_read, E0, outE, outB);
    } else {
        // ---- fallback: exact CSR of records (10.24 MB + scan arrays) ----
        float4* feat   = (float4*)d_ws;                    // 640000 recs
        int* counts    = (int*)((char*)d_ws + (size_t)N_EDGES * sizeof(float4));
        int* offsets   = counts + N_NODES;
        int* cursors   = offsets + N_NODES;
        int* prefix    = cursors + N_NODES;
        int* blockSums = prefix + N_NODES;
        hipMemsetAsync(counts, 0, N_NODES * sizeof(int), stream);
        count_kernel<<<(N_EDGES + 255)/256, 256, 0, stream>>>(receivers, counts);
        scan_blocks<<<SCAN_NB, SCAN_B, 0, stream>>>(counts, prefix, blockSums);
        scan_finalize<<<SCAN_NB, SCAN_B, 0, stream>>>(prefix, blockSums, offsets, cursors);
        scatter_rec_kernel<<<(N_EDGES + 255)/256, 256, 0, stream>>>(
            vectors, senders, receivers, species, cursors, feat);
        ace_node_csr<<<(NPAIRS + WPB - 1)/WPB, TPB, 0, stream>>>(
            feat, counts, offsets, species, node_mask,
            wA, c_pair, c_read, E0, outE, outB);
    }
}